// Round 1
// baseline (585.840 us; speedup 1.0000x reference)
//
#include <hip/hip_runtime.h>
#include <hip/hip_bf16.h>
#include <stdint.h>

// ---------------------------------------------------------------------------
// FacebookAdaptiveSoftmax forward on MI355X (gfx950)
//   out[4096, 50259] = concat(x@head_w^T, (x@t0w1^T)@t0w2^T * m0, (x@t1w1^T)@t1w2^T * m1)
//   new_head_target[4096] appended flat (as float)
// Strategy: cast everything to bf16 (padded to 128-col tiles) in ws, run
// m97-structure MFMA GEMMs (128x128 tile, BK=32, global_load_lds w=16).
// ---------------------------------------------------------------------------

typedef float  f32x4  __attribute__((ext_vector_type(4)));
typedef short  short8 __attribute__((ext_vector_type(8)));

#define CUT0 10000
#define CUT1 40000
#define CUT2 50257
#define NROWS 4096
#define LDC   50259L

__device__ __forceinline__ void gload16(const void* g, void* l) {
    __builtin_amdgcn_global_load_lds(
        (__attribute__((address_space(1))) void*)(g),
        (__attribute__((address_space(3))) void*)(l), 16, 0, 0);
}

__device__ __forceinline__ unsigned short f2bf(float f) {
    unsigned int u = __float_as_uint(f);
    u += 0x7fffu + ((u >> 16) & 1u);   // round-to-nearest-even
    return (unsigned short)(u >> 16);
}

// f32 [rows,K] -> bf16 [rowsPad,K], zero-filling pad rows. K = 2^lk.
__global__ void cast_pad_kernel(const float* __restrict__ in,
                                unsigned short* __restrict__ op,
                                int rows, int lk, long total4) {
    long i = blockIdx.x * (long)blockDim.x + threadIdx.x;
    const long stride = (long)gridDim.x * blockDim.x;
    for (; i < total4; i += stride) {
        const long e = i << 2;              // element index (x4)
        const long row = e >> lk;
        ushort4 o;
        if (row < rows) {
            const float4 v = *(const float4*)(in + e);
            o.x = f2bf(v.x); o.y = f2bf(v.y); o.z = f2bf(v.z); o.w = f2bf(v.w);
        } else {
            o.x = 0; o.y = 0; o.z = 0; o.w = 0;
        }
        *(ushort4*)(op + e) = o;
    }
}

__global__ void target_kernel(const int* __restrict__ tgt,
                              float* __restrict__ outT,
                              float* __restrict__ m0f,
                              float* __restrict__ m1f, int n) {
    const int i = blockIdx.x * blockDim.x + threadIdx.x;
    if (i < n) {
        const int t = tgt[i];
        const bool b0 = (t >= CUT0) && (t < CUT1);
        const bool b1 = (t >= CUT1) && (t < CUT2);
        m0f[i] = b0 ? 1.0f : 0.0f;
        m1f[i] = b1 ? 1.0f : 0.0f;
        const int nt = b0 ? CUT0 : (b1 ? (CUT0 + 1) : t);
        outT[i] = (float)nt;
    }
}

// C = A @ B^T.  A: bf16 [M,K] row-major (M = grid.y*128, multiple of 128).
// B: bf16 [NP,K] row-major, NP multiple of 128 (zero-padded rows).
// OUT_BF16==0: Cf[row*ldc + col] = acc * rowMask[row]  (col < width)
// OUT_BF16==1: Cb[row*ldc + col] = bf16(acc)           (col < width)
template<int OUT_BF16>
__global__ __launch_bounds__(256)
void gemm_bt_kernel(const unsigned short* __restrict__ A,
                    const unsigned short* __restrict__ B,
                    float* __restrict__ Cf,
                    unsigned short* __restrict__ Cb,
                    const float* __restrict__ rowMask,
                    int K, long ldc, int width) {
    __shared__ unsigned short As[128 * 32];
    __shared__ unsigned short Bs[128 * 32];

    const int tid  = threadIdx.x;
    const int lane = tid & 63;
    const int wave = tid >> 6;
    const int wr   = wave >> 1;            // wave row 0..1
    const int wc   = wave & 1;             // wave col 0..1

    const long bm = blockIdx.y;
    const long bn = blockIdx.x;

    // staging: thread t covers 8 bf16 at flat = t*8 (+2048 for 2nd half)
    const int s_row = tid >> 2;            // 0..63
    const int s_col = (tid & 3) << 3;      // 0,8,16,24

    const unsigned short* pA = A + (bm * 128 + s_row) * (long)K + s_col;
    const unsigned short* pB = B + (bn * 128 + s_row) * (long)K + s_col;

    char* asb = (char*)As + wave * 1024;   // wave-uniform LDS staging base
    char* bsb = (char*)Bs + wave * 1024;

    f32x4 acc[4][4];
#pragma unroll
    for (int m = 0; m < 4; m++)
#pragma unroll
        for (int n = 0; n < 4; n++) acc[m][n] = (f32x4){0.f, 0.f, 0.f, 0.f};

    const int f_r = lane & 15;             // row-in-16 for A/B frags
    const int f_k = (lane >> 4) << 3;      // k offset 0/8/16/24

    for (int k0 = 0; k0 < K; k0 += 32) {
        gload16(pA + k0,                asb);
        gload16(pA + k0 + 64L * K,      asb + 4096);
        gload16(pB + k0,                bsb);
        gload16(pB + k0 + 64L * K,      bsb + 4096);
        __syncthreads();

        short8 af[4], bfr[4];
#pragma unroll
        for (int m = 0; m < 4; m++)
            af[m] = *(const short8*)&As[(wr * 64 + m * 16 + f_r) * 32 + f_k];
#pragma unroll
        for (int n = 0; n < 4; n++)
            bfr[n] = *(const short8*)&Bs[(wc * 64 + n * 16 + f_r) * 32 + f_k];

#pragma unroll
        for (int m = 0; m < 4; m++)
#pragma unroll
            for (int n = 0; n < 4; n++)
                acc[m][n] = __builtin_amdgcn_mfma_f32_16x16x32_bf16(
                    af[m], bfr[n], acc[m][n], 0, 0, 0);
        __syncthreads();
    }

    // epilogue: C/D layout col = lane&15, row = (lane>>4)*4 + j  [m89-verified]
    const int c_col  = lane & 15;
    const int c_row4 = (lane >> 4) << 2;

#pragma unroll
    for (int m = 0; m < 4; m++) {
#pragma unroll
        for (int j = 0; j < 4; j++) {
            const long grow = bm * 128 + wr * 64 + m * 16 + c_row4 + j;
            float msk = 1.0f;
            if (OUT_BF16 == 0 && rowMask) msk = rowMask[grow];
#pragma unroll
            for (int n = 0; n < 4; n++) {
                const int gcol = (int)(bn * 128) + wc * 64 + n * 16 + c_col;
                if (gcol < width) {
                    if (OUT_BF16 == 0)
                        Cf[grow * ldc + gcol] = acc[m][n][j] * msk;
                    else
                        Cb[grow * ldc + gcol] = f2bf(acc[m][n][j]);
                }
            }
        }
    }
}

extern "C" void kernel_launch(void* const* d_in, const int* in_sizes, int n_in,
                              void* d_out, int out_size, void* d_ws, size_t ws_size,
                              hipStream_t stream) {
    const float* x      = (const float*)d_in[0];   // [4096,1024]
    const int*   target = (const int*)  d_in[1];   // [4096]
    const float* head_w = (const float*)d_in[2];   // [10002,1024]
    const float* t0_w1  = (const float*)d_in[3];   // [256,1024]
    const float* t0_w2  = (const float*)d_in[4];   // [30000,256]
    const float* t1_w1  = (const float*)d_in[5];   // [64,1024]
    const float* t1_w2  = (const float*)d_in[6];   // [10257,64]
    float* out = (float*)d_out;

    // ---- ws layout (bytes), all 256-aligned ----
    char* ws = (char*)d_ws;
    unsigned short* xb    = (unsigned short*)(ws + 0);          // 4096x1024
    unsigned short* hwb   = (unsigned short*)(ws + 8388608);    // 10112x1024
    unsigned short* t0w1b = (unsigned short*)(ws + 29097984);   // 256x1024
    unsigned short* t0w2b = (unsigned short*)(ws + 29622272);   // 30080x256
    unsigned short* t1w1b = (unsigned short*)(ws + 45023232);   // 128x1024
    unsigned short* t1w2b = (unsigned short*)(ws + 45285376);   // 10368x64
    unsigned short* h0    = (unsigned short*)(ws + 46612480);   // 4096x256
    unsigned short* h1    = (unsigned short*)(ws + 48709632);   // 4096x64
    float*          m0f   = (float*)        (ws + 49233920);    // 4096
    float*          m1f   = (float*)        (ws + 49250304);    // 4096

    auto blocks = [](long total4) {
        long b = (total4 + 255) / 256;
        return (unsigned)(b > 8192 ? 8192 : b);
    };

    // ---- casts to bf16 (+ zero row padding) ----
    {
        long t4;
        t4 = 4096L * 1024 / 4;
        cast_pad_kernel<<<blocks(t4), 256, 0, stream>>>(x, xb, 4096, 10, t4);
        t4 = 10112L * 1024 / 4;
        cast_pad_kernel<<<blocks(t4), 256, 0, stream>>>(head_w, hwb, 10002, 10, t4);
        t4 = 256L * 1024 / 4;
        cast_pad_kernel<<<blocks(t4), 256, 0, stream>>>(t0_w1, t0w1b, 256, 10, t4);
        t4 = 30080L * 256 / 4;
        cast_pad_kernel<<<blocks(t4), 256, 0, stream>>>(t0_w2, t0w2b, 30000, 8, t4);
        t4 = 128L * 1024 / 4;
        cast_pad_kernel<<<blocks(t4), 256, 0, stream>>>(t1_w1, t1w1b, 64, 10, t4);
        t4 = 10368L * 64 / 4;
        cast_pad_kernel<<<blocks(t4), 256, 0, stream>>>(t1_w2, t1w2b, 10257, 6, t4);
    }

    // ---- new_head_target + masks ----
    target_kernel<<<16, 256, 0, stream>>>(target, out + 4096L * LDC, m0f, m1f, NROWS);

    // ---- hidden projections: h0 = bf16(x @ t0w1^T) [4096,256]; h1 [4096,64] ----
    gemm_bt_kernel<1><<<dim3(2, 32), 256, 0, stream>>>(
        xb, t0w1b, nullptr, h0, nullptr, 1024, 256L, 256);
    gemm_bt_kernel<1><<<dim3(1, 32), 256, 0, stream>>>(
        xb, t1w1b, nullptr, h1, nullptr, 1024, 64L, 64);

    // ---- head: out[:, 0:10002] = x @ head_w^T ----
    gemm_bt_kernel<0><<<dim3(79, 32), 256, 0, stream>>>(
        xb, hwb, out, nullptr, nullptr, 1024, LDC, 10002);

    // ---- tail0: out[:, 10002:40002] = (h0 @ t0w2^T) * m0 ----
    gemm_bt_kernel<0><<<dim3(235, 32), 256, 0, stream>>>(
        h0, t0w2b, out + 10002, nullptr, m0f, 256, LDC, 30000);

    // ---- tail1: out[:, 40002:50259] = (h1 @ t1w2^T) * m1 ----
    gemm_bt_kernel<0><<<dim3(81, 32), 256, 0, stream>>>(
        h1, t1w2b, out + 40002, nullptr, m1f, 64, LDC, 10257);
}

// Round 2
// 465.291 us; speedup vs baseline: 1.2591x; 1.2591x over previous
//
#include <hip/hip_runtime.h>
#include <hip/hip_bf16.h>
#include <stdint.h>

// ---------------------------------------------------------------------------
// FacebookAdaptiveSoftmax forward on MI355X (gfx950)
//   out[4096, 50259] = concat(x@head_w^T, (x@t0w1^T)@t0w2^T * m0, (x@t1w1^T)@t1w2^T * m1)
//   new_head_target[4096] appended flat (as float)
// R2: GROUP_M=8 + XCD-chunked swizzle (panel L2 reuse), swapped-operand MFMA
// epilogue (4 consecutive cols/lane -> 16B stores), merged hidden GEMM,
// 16B-wide casts.
// ---------------------------------------------------------------------------

typedef float  f32x4   __attribute__((ext_vector_type(4)));
typedef short  short8  __attribute__((ext_vector_type(8)));
typedef unsigned short ushort8 __attribute__((ext_vector_type(8)));

#define CUT0 10000
#define CUT1 40000
#define CUT2 50257
#define NROWS 4096
#define LDC   50259L

__device__ __forceinline__ void gload16(const void* g, void* l) {
    __builtin_amdgcn_global_load_lds(
        (__attribute__((address_space(1))) void*)(g),
        (__attribute__((address_space(3))) void*)(l), 16, 0, 0);
}

__device__ __forceinline__ unsigned short f2bf(float f) {
    unsigned int u = __float_as_uint(f);
    u += 0x7fffu + ((u >> 16) & 1u);   // round-to-nearest-even
    return (unsigned short)(u >> 16);
}

// f32 [rows,K] -> bf16 [rowsPad,K], zero-filling pad rows. K = 2^lk. 8 elem/thread.
__global__ void cast_pad_kernel(const float* __restrict__ in,
                                unsigned short* __restrict__ op,
                                int rows, int lk, long total8) {
    long i = blockIdx.x * (long)blockDim.x + threadIdx.x;
    const long stride = (long)gridDim.x * blockDim.x;
    for (; i < total8; i += stride) {
        const long e = i << 3;              // element index (x8)
        const long row = e >> lk;
        ushort8 o;
        if (row < rows) {
            const float4 v0 = *(const float4*)(in + e);
            const float4 v1 = *(const float4*)(in + e + 4);
            o[0] = f2bf(v0.x); o[1] = f2bf(v0.y); o[2] = f2bf(v0.z); o[3] = f2bf(v0.w);
            o[4] = f2bf(v1.x); o[5] = f2bf(v1.y); o[6] = f2bf(v1.z); o[7] = f2bf(v1.w);
        } else {
            o = (ushort8)0;
        }
        *(ushort8*)(op + e) = o;
    }
}

__global__ void target_kernel(const int* __restrict__ tgt,
                              float* __restrict__ outT,
                              float* __restrict__ m0f,
                              float* __restrict__ m1f, int n) {
    const int i = blockIdx.x * blockDim.x + threadIdx.x;
    if (i < n) {
        const int t = tgt[i];
        const bool b0 = (t >= CUT0) && (t < CUT1);
        const bool b1 = (t >= CUT1) && (t < CUT2);
        m0f[i] = b0 ? 1.0f : 0.0f;
        m1f[i] = b1 ? 1.0f : 0.0f;
        const int nt = b0 ? CUT0 : (b1 ? (CUT0 + 1) : t);
        outT[i] = (float)nt;
    }
}

// C = A @ B^T.  A: bf16 [M, lda] row-major, first K cols used; M = 32*128.
// B: bf16 [NP, K] row-major (packed), NP = NB*128 (zero-padded rows).
// Swapped-operand MFMA: acc = mfma(b_frag, a_frag) so output ROW field
// ((lane>>4)*4+j) indexes B-rows (gcol) -> 4 consecutive cols per lane.
// OUT_BF16==0: Cf[row*ldc + col] = acc * rowMask[row]  (col < width)
// OUT_BF16==1: Cb[row*ldc + col] = bf16(acc)           (col < width)
template<int OUT_BF16>
__global__ __launch_bounds__(256)
void gemm_bt_kernel(const unsigned short* __restrict__ A,
                    const unsigned short* __restrict__ B,
                    float* __restrict__ Cf,
                    unsigned short* __restrict__ Cb,
                    const float* __restrict__ rowMask,
                    int K, int lda, long ldc, int width, int NB) {
    __shared__ unsigned short As[128 * 32];
    __shared__ unsigned short Bs[128 * 32];

    const int tid  = threadIdx.x;
    const int lane = tid & 63;
    const int wave = tid >> 6;
    const int wr   = wave >> 1;            // wave row 0..1 (M)
    const int wc   = wave & 1;             // wave col 0..1 (N)

    // --- bijective XCD-chunk swizzle (m204) + GROUP_M=8 (bm-fastest) ---
    const int nwg = gridDim.x;             // = NB * 32
    const int q = nwg >> 3, r = nwg & 7;
    const int xcd = blockIdx.x & 7, loc = blockIdx.x >> 3;
    const int L = (xcd < r ? xcd * (q + 1) : r * (q + 1) + (xcd - r) * q) + loc;
    const int g = L / (NB << 3);           // bm group 0..3
    const int t = L - g * (NB << 3);
    const long bm = (g << 3) + (t & 7);
    const long bn = t >> 3;

    // staging: thread t covers 16B at flat byte = tid*16 (+4096 for 2nd half)
    const int s_row = tid >> 2;            // 0..63
    const int s_col = (tid & 3) << 3;      // 0,8,16,24

    const unsigned short* pA = A + (bm * 128 + s_row) * (long)lda + s_col;
    const unsigned short* pB = B + (bn * 128 + s_row) * (long)K + s_col;

    char* asb = (char*)As + wave * 1024;   // wave-uniform LDS staging base
    char* bsb = (char*)Bs + wave * 1024;

    f32x4 acc[4][4];
#pragma unroll
    for (int m = 0; m < 4; m++)
#pragma unroll
        for (int n = 0; n < 4; n++) acc[m][n] = (f32x4){0.f, 0.f, 0.f, 0.f};

    const int f_r = lane & 15;             // row-in-16 for A/B frags
    const int f_k = (lane >> 4) << 3;      // k offset 0/8/16/24

    for (int k0 = 0; k0 < K; k0 += 32) {
        gload16(pA + k0,                  asb);
        gload16(pA + k0 + 64L * lda,      asb + 4096);
        gload16(pB + k0,                  bsb);
        gload16(pB + k0 + 64L * K,        bsb + 4096);
        __syncthreads();

        short8 af[4], bfr[4];
#pragma unroll
        for (int m = 0; m < 4; m++)
            af[m] = *(const short8*)&As[(wr * 64 + m * 16 + f_r) * 32 + f_k];
#pragma unroll
        for (int n = 0; n < 4; n++)
            bfr[n] = *(const short8*)&Bs[(wc * 64 + n * 16 + f_r) * 32 + f_k];

        // swapped operands: first operand (bfr) rows -> D row field -> gcol
#pragma unroll
        for (int m = 0; m < 4; m++)
#pragma unroll
            for (int n = 0; n < 4; n++)
                acc[m][n] = __builtin_amdgcn_mfma_f32_16x16x32_bf16(
                    bfr[n], af[m], acc[m][n], 0, 0, 0);
        __syncthreads();
    }

    // epilogue (swapped): grow uses lane&15 (A-rows), gcol uses (lane>>4)*4+j (B-rows)
    const int c_a  = lane & 15;
    const int c_b4 = (lane >> 4) << 2;

#pragma unroll
    for (int m = 0; m < 4; m++) {
        const long grow = bm * 128 + wr * 64 + m * 16 + c_a;
        if (OUT_BF16 == 0) {
            float* rp = Cf + grow * ldc;
            const float msk = rowMask ? rowMask[grow] : 1.0f;
#pragma unroll
            for (int n = 0; n < 4; n++) {
                const int gcb = (int)(bn * 128) + wc * 64 + n * 16 + c_b4;
                f32x4 v = acc[m][n];
                v[0] *= msk; v[1] *= msk; v[2] *= msk; v[3] *= msk;
                if (gcb + 3 < width) {
                    __builtin_memcpy(rp + gcb, &v, 16);   // ldc odd -> 4B-aligned
                } else {
#pragma unroll
                    for (int j = 0; j < 4; j++)
                        if (gcb + j < width) rp[gcb + j] = v[j];
                }
            }
        } else {
            unsigned short* rp = Cb + grow * ldc;
#pragma unroll
            for (int n = 0; n < 4; n++) {
                const int gcb = (int)(bn * 128) + wc * 64 + n * 16 + c_b4;
                const f32x4 v = acc[m][n];
                ushort4 o;
                o.x = f2bf(v[0]); o.y = f2bf(v[1]); o.z = f2bf(v[2]); o.w = f2bf(v[3]);
                if (gcb + 3 < width) {
                    *(ushort4*)(rp + gcb) = o;            // 8B-aligned (ldc mult of 4)
                } else {
                    unsigned short tmp[4] = {o.x, o.y, o.z, o.w};
#pragma unroll
                    for (int j = 0; j < 4; j++)
                        if (gcb + j < width) rp[gcb + j] = tmp[j];
                }
            }
        }
    }
}

extern "C" void kernel_launch(void* const* d_in, const int* in_sizes, int n_in,
                              void* d_out, int out_size, void* d_ws, size_t ws_size,
                              hipStream_t stream) {
    const float* x      = (const float*)d_in[0];   // [4096,1024]
    const int*   target = (const int*)  d_in[1];   // [4096]
    const float* head_w = (const float*)d_in[2];   // [10002,1024]
    const float* t0_w1  = (const float*)d_in[3];   // [256,1024]
    const float* t0_w2  = (const float*)d_in[4];   // [30000,256]
    const float* t1_w1  = (const float*)d_in[5];   // [64,1024]
    const float* t1_w2  = (const float*)d_in[6];   // [10257,64]
    float* out = (float*)d_out;

    // ---- ws layout (bytes) ----
    char* ws = (char*)d_ws;
    unsigned short* xb    = (unsigned short*)(ws + 0);          // 4096x1024
    unsigned short* hwb   = (unsigned short*)(ws + 8388608);    // 10112x1024
    unsigned short* w01b  = (unsigned short*)(ws + 29097984);   // 384x1024 (t0w1|t1w1|0)
    unsigned short* t0w2b = (unsigned short*)(ws + 29884416);   // 30080x256
    unsigned short* t1w2b = (unsigned short*)(ws + 45285376);   // 10368x64
    unsigned short* h01   = (unsigned short*)(ws + 46612480);   // 4096x384 bf16
    float*          m0f   = (float*)        (ws + 49758208);    // 4096
    float*          m1f   = (float*)        (ws + 49774592);    // 4096

    auto blocks8 = [](long total8) {
        long b = (total8 + 255) / 256;
        return (unsigned)(b > 8192 ? 8192 : b);
    };

    // ---- casts to bf16 (+ zero row padding) ----
    {
        long t8;
        t8 = 4096L * 1024 / 8;
        cast_pad_kernel<<<blocks8(t8), 256, 0, stream>>>(x, xb, 4096, 10, t8);
        t8 = 10112L * 1024 / 8;
        cast_pad_kernel<<<blocks8(t8), 256, 0, stream>>>(head_w, hwb, 10002, 10, t8);
        // merged hidden weights: rows 0-255 = t0w1, rows 256-319 = t1w1, 320-383 = 0
        t8 = 384L * 1024 / 8;   // first call zero-fills rows 256..383
        cast_pad_kernel<<<blocks8(t8), 256, 0, stream>>>(t0_w1, w01b, 256, 10, t8);
        t8 = 64L * 1024 / 8;    // overwrite rows 256..319 with t1w1
        cast_pad_kernel<<<blocks8(t8), 256, 0, stream>>>(t1_w1, w01b + 256L * 1024, 64, 10, t8);
        t8 = 30080L * 256 / 8;
        cast_pad_kernel<<<blocks8(t8), 256, 0, stream>>>(t0_w2, t0w2b, 30000, 8, t8);
        t8 = 10368L * 64 / 8;
        cast_pad_kernel<<<blocks8(t8), 256, 0, stream>>>(t1_w2, t1w2b, 10257, 6, t8);
    }

    // ---- new_head_target + masks ----
    target_kernel<<<16, 256, 0, stream>>>(target, out + 4096L * LDC, m0f, m1f, NROWS);

    // ---- merged hidden: h01[4096,384] = bf16(x @ [t0w1;t1w1;0]^T) ----
    gemm_bt_kernel<1><<<dim3(3 * 32), 256, 0, stream>>>(
        xb, w01b, nullptr, h01, nullptr, 1024, 1024, 384L, 384, 3);

    // ---- head: out[:, 0:10002] = x @ head_w^T ----
    gemm_bt_kernel<0><<<dim3(79 * 32), 256, 0, stream>>>(
        xb, hwb, out, nullptr, nullptr, 1024, 1024, LDC, 10002, 79);

    // ---- tail0: out[:, 10002:40002] = (h0 @ t0w2^T) * m0 ----
    gemm_bt_kernel<0><<<dim3(235 * 32), 256, 0, stream>>>(
        h01, t0w2b, out + 10002, nullptr, m0f, 256, 384, LDC, 30000, 235);

    // ---- tail1: out[:, 40002:50259] = (h1 @ t1w2^T) * m1 ----
    gemm_bt_kernel<0><<<dim3(81 * 32), 256, 0, stream>>>(
        h01 + 256, t1w2b, out + 40002, nullptr, m1f, 64, 384, LDC, 10257, 81);
}

// Round 3
// 437.842 us; speedup vs baseline: 1.3380x; 1.0627x over previous
//
#include <hip/hip_runtime.h>
#include <hip/hip_bf16.h>
#include <stdint.h>

// ---------------------------------------------------------------------------
// FacebookAdaptiveSoftmax forward on MI355X (gfx950)
//   out[4096, 50259] = concat(x@head_w^T, (x@t0w1^T)@t0w2^T * m0, (x@t1w1^T)@t1w2^T * m1)
//   new_head_target[4096] appended flat (as float)
// R3: 8-phase 256x256 BK=64 schedule (T2 swizzle + T3/T4 counted vmcnt + T5
// setprio) for the three output GEMMs; m97-structure kernel kept for the
// small hidden projection; swapped-operand MFMA epilogue (16B col stores).
// ---------------------------------------------------------------------------

typedef float  f32x4   __attribute__((ext_vector_type(4)));
typedef short  short8  __attribute__((ext_vector_type(8)));
typedef unsigned short ushort8 __attribute__((ext_vector_type(8)));

#define CUT0 10000
#define CUT1 40000
#define CUT2 50257
#define NROWS 4096
#define LDC   50259L

__device__ __forceinline__ void gload16(const void* g, void* l) {
    __builtin_amdgcn_global_load_lds(
        (__attribute__((address_space(1))) void*)(g),
        (__attribute__((address_space(3))) void*)(l), 16, 0, 0);
}

__device__ __forceinline__ unsigned short f2bf(float f) {
    unsigned int u = __float_as_uint(f);
    u += 0x7fffu + ((u >> 16) & 1u);   // round-to-nearest-even
    return (unsigned short)(u >> 16);
}

__device__ __forceinline__ short8 dsr128(unsigned addr) {
    f32x4 r;
    asm volatile("ds_read_b128 %0, %1" : "=v"(r) : "v"(addr));
    return __builtin_bit_cast(short8, r);
}

__device__ __forceinline__ f32x4 mfma16(short8 a, short8 b, f32x4 c) {
    return __builtin_amdgcn_mfma_f32_16x16x32_bf16(a, b, c, 0, 0, 0);
}

// f32 [rows,K] -> bf16 [rowsPad,K], zero-filling pad rows. K = 2^lk. 8 elem/thread.
__global__ void cast_pad_kernel(const float* __restrict__ in,
                                unsigned short* __restrict__ op,
                                int rows, int lk, long total8) {
    long i = blockIdx.x * (long)blockDim.x + threadIdx.x;
    const long stride = (long)gridDim.x * blockDim.x;
    for (; i < total8; i += stride) {
        const long e = i << 3;
        const long row = e >> lk;
        ushort8 o;
        if (row < rows) {
            const float4 v0 = *(const float4*)(in + e);
            const float4 v1 = *(const float4*)(in + e + 4);
            o[0] = f2bf(v0.x); o[1] = f2bf(v0.y); o[2] = f2bf(v0.z); o[3] = f2bf(v0.w);
            o[4] = f2bf(v1.x); o[5] = f2bf(v1.y); o[6] = f2bf(v1.z); o[7] = f2bf(v1.w);
        } else {
            o = (ushort8)0;
        }
        *(ushort8*)(op + e) = o;
    }
}

__global__ void target_kernel(const int* __restrict__ tgt,
                              float* __restrict__ outT,
                              float* __restrict__ m0f,
                              float* __restrict__ m1f, int n) {
    const int i = blockIdx.x * blockDim.x + threadIdx.x;
    if (i < n) {
        const int t = tgt[i];
        const bool b0 = (t >= CUT0) && (t < CUT1);
        const bool b1 = (t >= CUT1) && (t < CUT2);
        m0f[i] = b0 ? 1.0f : 0.0f;
        m1f[i] = b1 ? 1.0f : 0.0f;
        const int nt = b0 ? CUT0 : (b1 ? (CUT0 + 1) : t);
        outT[i] = (float)nt;
    }
}

// ===========================================================================
// 8-phase 256x256 GEMM, C = A @ B^T (f32 out, optional row mask).
// A: bf16 [NM*256, lda]; B: bf16 [NB*256, ldb] (zero-padded rows), K = nkt*64.
// 8 waves = 2M x 4N; per-wave tile 128x64; LDS 128KB (2 dbuf x (A 32K + B 32K)).
// Swizzle: byte-col ^= ((row>>2)&1)<<5 (on gload SOURCE and ds_read addr).
// Swapped MFMA operands: D row field = B-row = output col (contiguous stores).
// ===========================================================================
#define STAGE2(MATP, LDM, RB, KCOL, LOFF)                                          \
    do {                                                                           \
        const unsigned short* _s0 = (MATP) + ((long)((RB) + (tid >> 3))) * (LDM) + (KCOL); \
        gload16(_s0, smem + (LOFF) + wave * 1024);                                 \
        const unsigned short* _s1 = (MATP) + ((long)((RB) + 64 + (tid >> 3))) * (LDM) + (KCOL); \
        gload16(_s1, smem + (LOFF) + 8192 + wave * 1024);                          \
    } while (0)

__global__ __launch_bounds__(512, 2)
void gemm8_kernel(const unsigned short* __restrict__ A,
                  const unsigned short* __restrict__ B,
                  float* __restrict__ Cf,
                  const float* __restrict__ rowMask,
                  int nkt, int lda, int ldb, long ldc, int width,
                  int NB, int NM) {
    __shared__ char smem[131072];

    const int tid  = threadIdx.x;
    const int lane = tid & 63;
    const int wave = tid >> 6;
    const int wr   = wave >> 2;            // M half 0..1
    const int wc   = wave & 3;             // N quarter 0..3

    // bijective XCD chunk + GROUP_M=4 (bm fastest); nwg % 8 == 0 for all calls
    const int nwg = NM * NB;
    const int q = nwg >> 3, r = nwg & 7;
    const int xcd = blockIdx.x & 7, loc = blockIdx.x >> 3;
    const int L = (xcd < r ? xcd * (q + 1) : r * (q + 1) + (xcd - r) * q) + loc;
    const int g = L / (NB * 4);
    const int t = L - g * (NB * 4);
    const long bm = g * 4 + (t & 3);
    const long bn = t >> 2;

    const long bmRow = bm * 256;
    const long bnRow = bn * 256;

    // staging source column (elems), pre-swizzled: ((tid&7)*8) ^ (((tid>>5)&1)<<4)
    const int scol = ((tid & 7) << 3) ^ (((tid >> 5) & 1) << 4);

    // ds_read per-lane address pieces
    const unsigned lane15 = lane & 15;
    const unsigned sw    = ((lane >> 2) & 1) << 5;
    const unsigned kcol0 = (((lane >> 4) << 4)) ^ sw;        // kk=0 byte col
    const unsigned kcol1 = (64u + ((lane >> 4) << 4)) ^ sw;  // kk=1 byte col
    const unsigned smemBase =
        (unsigned)(size_t)(__attribute__((address_space(3))) char*)smem;
    const unsigned aB0 = smemBase + wr * 16384 + lane15 * 128;
    const unsigned bB0 = smemBase + 32768 + (wc >> 1) * 16384 +
                         ((wc & 1) * 64 + lane15) * 128;

    f32x4 acc[8][4];
#pragma unroll
    for (int m = 0; m < 8; m++)
#pragma unroll
        for (int n = 0; n < 4; n++) acc[m][n] = (f32x4){0.f, 0.f, 0.f, 0.f};

    // ---- prologue: stage K-tile 0 into buf 0 (8 loads/thread) ----
    STAGE2(A, lda, bmRow,       scol, 0);
    STAGE2(A, lda, bmRow + 128, scol, 16384);
    STAGE2(B, ldb, bnRow,       scol, 32768);
    STAGE2(B, ldb, bnRow + 128, scol, 49152);

    short8 afk0[4], afk1[4], bA0[2], bA1[2], bH0[2], bH1[2];

    for (int kt = 0; kt < nkt; ++kt) {
        const int c  = kt & 1;
        const bool pf = (kt + 1) < nkt;
        const int kc = (kt + 1) * 64 + scol;
        const unsigned aBase = aB0 + c * 65536;
        const unsigned bBase = bB0 + c * 65536;
        const unsigned lOff  = (c ^ 1) * 65536;

        // -------- phase 0 : Q0 = (mLo, nLo) --------
        if (pf) {
            STAGE2(A, lda, bmRow, kc, lOff);
            asm volatile("s_waitcnt vmcnt(2)" ::: "memory");
        } else {
            asm volatile("s_waitcnt vmcnt(0)" ::: "memory");
        }
        __builtin_amdgcn_s_barrier();
#pragma unroll
        for (int mf = 0; mf < 4; ++mf) {
            afk0[mf] = dsr128(aBase + mf * 2048 + kcol0);
            afk1[mf] = dsr128(aBase + mf * 2048 + kcol1);
        }
#pragma unroll
        for (int nf = 0; nf < 2; ++nf) {
            bA0[nf] = dsr128(bBase + nf * 2048 + kcol0);
            bA1[nf] = dsr128(bBase + nf * 2048 + kcol1);
        }
        asm volatile("s_waitcnt lgkmcnt(0)" ::: "memory");
        __builtin_amdgcn_sched_barrier(0);
        __builtin_amdgcn_s_setprio(1);
#pragma unroll
        for (int mf = 0; mf < 4; ++mf)
#pragma unroll
            for (int nf = 0; nf < 2; ++nf) {
                acc[mf][nf] = mfma16(bA0[nf], afk0[mf], acc[mf][nf]);
                acc[mf][nf] = mfma16(bA1[nf], afk1[mf], acc[mf][nf]);
            }
        __builtin_amdgcn_s_setprio(0);
        __builtin_amdgcn_s_barrier();

        // -------- phase 1 : Q1 = (mLo, nHi) --------
#pragma unroll
        for (int nf = 0; nf < 2; ++nf) {
            bH0[nf] = dsr128(bBase + (2 + nf) * 2048 + kcol0);
            bH1[nf] = dsr128(bBase + (2 + nf) * 2048 + kcol1);
        }
        if (pf) STAGE2(A, lda, bmRow + 128, kc, lOff + 16384);
        __builtin_amdgcn_s_barrier();
        asm volatile("s_waitcnt lgkmcnt(0)" ::: "memory");
        __builtin_amdgcn_sched_barrier(0);
        __builtin_amdgcn_s_setprio(1);
#pragma unroll
        for (int mf = 0; mf < 4; ++mf)
#pragma unroll
            for (int nf = 0; nf < 2; ++nf) {
                acc[mf][2 + nf] = mfma16(bH0[nf], afk0[mf], acc[mf][2 + nf]);
                acc[mf][2 + nf] = mfma16(bH1[nf], afk1[mf], acc[mf][2 + nf]);
            }
        __builtin_amdgcn_s_setprio(0);
        __builtin_amdgcn_s_barrier();

        // -------- phase 2 : Q2 = (mHi, nHi) --------
#pragma unroll
        for (int mf = 0; mf < 4; ++mf) {
            afk0[mf] = dsr128(aBase + (4 + mf) * 2048 + kcol0);
            afk1[mf] = dsr128(aBase + (4 + mf) * 2048 + kcol1);
        }
        if (pf) STAGE2(B, ldb, bnRow, kc, lOff + 32768);
        __builtin_amdgcn_s_barrier();
        asm volatile("s_waitcnt lgkmcnt(0)" ::: "memory");
        __builtin_amdgcn_sched_barrier(0);
        __builtin_amdgcn_s_setprio(1);
#pragma unroll
        for (int mf = 0; mf < 4; ++mf)
#pragma unroll
            for (int nf = 0; nf < 2; ++nf) {
                acc[4 + mf][2 + nf] = mfma16(bH0[nf], afk0[mf], acc[4 + mf][2 + nf]);
                acc[4 + mf][2 + nf] = mfma16(bH1[nf], afk1[mf], acc[4 + mf][2 + nf]);
            }
        __builtin_amdgcn_s_setprio(0);
        __builtin_amdgcn_s_barrier();

        // -------- phase 3 : Q3 = (mHi, nLo) --------
#pragma unroll
        for (int nf = 0; nf < 2; ++nf) {
            bA0[nf] = dsr128(bBase + nf * 2048 + kcol0);
            bA1[nf] = dsr128(bBase + nf * 2048 + kcol1);
        }
        if (pf) STAGE2(B, ldb, bnRow + 128, kc, lOff + 49152);
        __builtin_amdgcn_s_barrier();
        asm volatile("s_waitcnt lgkmcnt(0)" ::: "memory");
        __builtin_amdgcn_sched_barrier(0);
        __builtin_amdgcn_s_setprio(1);
#pragma unroll
        for (int mf = 0; mf < 4; ++mf)
#pragma unroll
            for (int nf = 0; nf < 2; ++nf) {
                acc[4 + mf][nf] = mfma16(bA0[nf], afk0[mf], acc[4 + mf][nf]);
                acc[4 + mf][nf] = mfma16(bA1[nf], afk1[mf], acc[4 + mf][nf]);
            }
        __builtin_amdgcn_s_setprio(0);
        __builtin_amdgcn_s_barrier();
    }

    // ---- epilogue: lane holds rows (lane&15), 4 consecutive cols ((lane>>4)*4)
    const int cb4 = (lane >> 4) << 2;
#pragma unroll
    for (int mf = 0; mf < 8; ++mf) {
        const long grow = bmRow + wr * 128 + mf * 16 + lane15;
        float* rp = Cf + grow * ldc;
        const float msk = rowMask ? rowMask[grow] : 1.0f;
#pragma unroll
        for (int nf = 0; nf < 4; ++nf) {
            const int gcb = (int)bnRow + wc * 64 + nf * 16 + cb4;
            f32x4 v = acc[mf][nf];
            v[0] *= msk; v[1] *= msk; v[2] *= msk; v[3] *= msk;
            if (gcb + 3 < width) {
                __builtin_memcpy(rp + gcb, &v, 16);   // ldc odd -> 4B-aligned
            } else {
#pragma unroll
                for (int j = 0; j < 4; ++j)
                    if (gcb + j < width) rp[gcb + j] = v[j];
            }
        }
    }
}

// ===========================================================================
// m97-structure 128x128 GEMM (bf16 out) — used only for the small hidden
// projection h01 = bf16(x @ [t0w1;t1w1;0]^T).  Proven in R1/R2.
// ===========================================================================
__global__ __launch_bounds__(256)
void gemm_bt_bf16_kernel(const unsigned short* __restrict__ A,
                         const unsigned short* __restrict__ B,
                         unsigned short* __restrict__ Cb,
                         int K, int lda, long ldc, int width, int NB) {
    __shared__ unsigned short As[128 * 32];
    __shared__ unsigned short Bs[128 * 32];

    const int tid  = threadIdx.x;
    const int lane = tid & 63;
    const int wave = tid >> 6;
    const int wr   = wave >> 1;
    const int wc   = wave & 1;

    const int nwg = gridDim.x;
    const int q = nwg >> 3, r = nwg & 7;
    const int xcd = blockIdx.x & 7, loc = blockIdx.x >> 3;
    const int L = (xcd < r ? xcd * (q + 1) : r * (q + 1) + (xcd - r) * q) + loc;
    const int g = L / (NB << 3);
    const int t = L - g * (NB << 3);
    const long bm = (g << 3) + (t & 7);
    const long bn = t >> 3;

    const int s_row = tid >> 2;
    const int s_col = (tid & 3) << 3;

    const unsigned short* pA = A + (bm * 128 + s_row) * (long)lda + s_col;
    const unsigned short* pB = B + (bn * 128 + s_row) * (long)K + s_col;

    char* asb = (char*)As + wave * 1024;
    char* bsb = (char*)Bs + wave * 1024;

    f32x4 acc[4][4];
#pragma unroll
    for (int m = 0; m < 4; m++)
#pragma unroll
        for (int n = 0; n < 4; n++) acc[m][n] = (f32x4){0.f, 0.f, 0.f, 0.f};

    const int f_r = lane & 15;
    const int f_k = (lane >> 4) << 3;

    for (int k0 = 0; k0 < K; k0 += 32) {
        gload16(pA + k0,             asb);
        gload16(pA + k0 + 64L * lda, asb + 4096);
        gload16(pB + k0,             bsb);
        gload16(pB + k0 + 64L * K,   bsb + 4096);
        __syncthreads();

        short8 af[4], bfr[4];
#pragma unroll
        for (int m = 0; m < 4; m++)
            af[m] = *(const short8*)&As[(wr * 64 + m * 16 + f_r) * 32 + f_k];
#pragma unroll
        for (int n = 0; n < 4; n++)
            bfr[n] = *(const short8*)&Bs[(wc * 64 + n * 16 + f_r) * 32 + f_k];

#pragma unroll
        for (int m = 0; m < 4; m++)
#pragma unroll
            for (int n = 0; n < 4; n++)
                acc[m][n] = __builtin_amdgcn_mfma_f32_16x16x32_bf16(
                    bfr[n], af[m], acc[m][n], 0, 0, 0);
        __syncthreads();
    }

    const int c_a  = lane & 15;
    const int c_b4 = (lane >> 4) << 2;
#pragma unroll
    for (int m = 0; m < 4; m++) {
        const long grow = bm * 128 + wr * 64 + m * 16 + c_a;
        unsigned short* rp = Cb + grow * ldc;
#pragma unroll
        for (int n = 0; n < 4; n++) {
            const int gcb = (int)(bn * 128) + wc * 64 + n * 16 + c_b4;
            const f32x4 v = acc[m][n];
            ushort4 o;
            o.x = f2bf(v[0]); o.y = f2bf(v[1]); o.z = f2bf(v[2]); o.w = f2bf(v[3]);
            if (gcb + 3 < width) {
                *(ushort4*)(rp + gcb) = o;
            } else {
                unsigned short tmp[4] = {o.x, o.y, o.z, o.w};
#pragma unroll
                for (int j = 0; j < 4; j++)
                    if (gcb + j < width) rp[gcb + j] = tmp[j];
            }
        }
    }
}

extern "C" void kernel_launch(void* const* d_in, const int* in_sizes, int n_in,
                              void* d_out, int out_size, void* d_ws, size_t ws_size,
                              hipStream_t stream) {
    const float* x      = (const float*)d_in[0];   // [4096,1024]
    const int*   target = (const int*)  d_in[1];   // [4096]
    const float* head_w = (const float*)d_in[2];   // [10002,1024]
    const float* t0_w1  = (const float*)d_in[3];   // [256,1024]
    const float* t0_w2  = (const float*)d_in[4];   // [30000,256]
    const float* t1_w1  = (const float*)d_in[5];   // [64,1024]
    const float* t1_w2  = (const float*)d_in[6];   // [10257,64]
    float* out = (float*)d_out;

    // ---- ws layout (bytes) ----
    char* ws = (char*)d_ws;
    unsigned short* xb    = (unsigned short*)(ws + 0);          // 4096x1024
    unsigned short* hwb   = (unsigned short*)(ws + 8388608);    // 10240x1024
    unsigned short* w01b  = (unsigned short*)(ws + 29360128);   // 384x1024 (t0w1|t1w1|0)
    unsigned short* t0w2b = (unsigned short*)(ws + 30146560);   // 30208x256
    unsigned short* t1w2b = (unsigned short*)(ws + 45613056);   // 10496x64
    unsigned short* h01   = (unsigned short*)(ws + 46956544);   // 4096x384 bf16
    float*          m0f   = (float*)        (ws + 50102272);    // 4096
    float*          m1f   = (float*)        (ws + 50118656);    // 4096

    auto blocks8 = [](long total8) {
        long b = (total8 + 255) / 256;
        return (unsigned)(b > 8192 ? 8192 : b);
    };

    // ---- casts to bf16 (+ zero row padding to 256-row tiles) ----
    {
        long t8;
        t8 = 4096L * 1024 / 8;
        cast_pad_kernel<<<blocks8(t8), 256, 0, stream>>>(x, xb, 4096, 10, t8);
        t8 = 10240L * 1024 / 8;
        cast_pad_kernel<<<blocks8(t8), 256, 0, stream>>>(head_w, hwb, 10002, 10, t8);
        t8 = 384L * 1024 / 8;   // zero-fills rows 256..383
        cast_pad_kernel<<<blocks8(t8), 256, 0, stream>>>(t0_w1, w01b, 256, 10, t8);
        t8 = 64L * 1024 / 8;    // overwrite rows 256..319 with t1w1
        cast_pad_kernel<<<blocks8(t8), 256, 0, stream>>>(t1_w1, w01b + 256L * 1024, 64, 10, t8);
        t8 = 30208L * 256 / 8;
        cast_pad_kernel<<<blocks8(t8), 256, 0, stream>>>(t0_w2, t0w2b, 30000, 8, t8);
        t8 = 10496L * 64 / 8;
        cast_pad_kernel<<<blocks8(t8), 256, 0, stream>>>(t1_w2, t1w2b, 10257, 6, t8);
    }

    // ---- new_head_target + masks ----
    target_kernel<<<16, 256, 0, stream>>>(target, out + 4096L * LDC, m0f, m1f, NROWS);

    // ---- merged hidden: h01[4096,384] = bf16(x @ [t0w1;t1w1;0]^T) ----
    gemm_bt_bf16_kernel<<<dim3(3 * 32), 256, 0, stream>>>(
        xb, w01b, h01, 1024, 1024, 384L, 384, 3);

    // ---- head: out[:, 0:10002] = x @ head_w^T  (16x40 tiles of 256^2) ----
    gemm8_kernel<<<dim3(640), 512, 0, stream>>>(
        xb, hwb, out, nullptr, 16, 1024, 1024, LDC, 10002, 40, 16);

    // ---- tail0: out[:, 10002:40002] = (h0 @ t0w2^T) * m0  (16x118) ----
    gemm8_kernel<<<dim3(1888), 512, 0, stream>>>(
        h01, t0w2b, out + 10002, m0f, 4, 384, 256, LDC, 30000, 118, 16);

    // ---- tail1: out[:, 40002:50259] = (h1 @ t1w2^T) * m1  (16x41) ----
    gemm8_kernel<<<dim3(656), 512, 0, stream>>>(
        h01 + 256, t1w2b, out + 40002, m1f, 1, 384, 64, LDC, 10257, 41, 16);
}

// Round 4
// 419.173 us; speedup vs baseline: 1.3976x; 1.0445x over previous
//
#include <hip/hip_runtime.h>
#include <hip/hip_bf16.h>
#include <stdint.h>

// ---------------------------------------------------------------------------
// FacebookAdaptiveSoftmax forward on MI355X (gfx950) — R4
//   out[4096, 50259] = concat(x@head_w^T, (x@t0w1^T)@t0w2^T * m0, (x@t1w1^T)@t1w2^T * m1)
//   new_head_target[4096] appended flat (as float)
// R4: 3 launches. (1) fused cast+target. (2) head GEMM (8-phase 256^2) + h01
// hidden GEMM fused in one launch. (3) tail0+tail1 fused, m97-128^2 structure
// (~3 blocks/CU for store/compute overlap; 8-phase at nkt<=4 was 1 block/CU
// with nothing to hide prologue/epilogue behind).
// ---------------------------------------------------------------------------

typedef float  f32x4   __attribute__((ext_vector_type(4)));
typedef short  short8  __attribute__((ext_vector_type(8)));
typedef unsigned short ushort8 __attribute__((ext_vector_type(8)));

#define CUT0 10000
#define CUT1 40000
#define CUT2 50257
#define LDC   50259L

__device__ __forceinline__ void gload16(const void* g, void* l) {
    __builtin_amdgcn_global_load_lds(
        (__attribute__((address_space(1))) void*)(g),
        (__attribute__((address_space(3))) void*)(l), 16, 0, 0);
}

__device__ __forceinline__ unsigned short f2bf(float f) {
    unsigned int u = __float_as_uint(f);
    u += 0x7fffu + ((u >> 16) & 1u);   // round-to-nearest-even
    return (unsigned short)(u >> 16);
}

__device__ __forceinline__ short8 dsr128(unsigned addr) {
    f32x4 r;
    asm volatile("ds_read_b128 %0, %1" : "=v"(r) : "v"(addr));
    return __builtin_bit_cast(short8, r);
}

__device__ __forceinline__ f32x4 mfma16(short8 a, short8 b, f32x4 c) {
    return __builtin_amdgcn_mfma_f32_16x16x32_bf16(a, b, c, 0, 0, 0);
}

// ===========================================================================
// Fused cast (5 segments, f32 -> bf16 with zero row padding) + target/masks.
// Segment rule: row < rowsA -> srcA[row]; rowsA <= row < rowsB ->
// srcB[row-rowsA]; else 0.  All row widths are powers of two (lk).
// ===========================================================================
struct CastSeg {
    const float* srcA;
    const float* srcB;
    unsigned short* dst;
    long rowsA, rowsB, total8;
    int lk, pad;
};
struct CastArgs {
    CastSeg s[5];
    long grand8;
    const int* tgt;
    float* outT;
    float* m0f;
    float* m1f;
};

__global__ __launch_bounds__(256)
void cast_all_kernel(CastArgs a) {
    // ---- target + masks (first 16 blocks handle 4096 rows) ----
    if (blockIdx.x < 16) {
        const int i = blockIdx.x * 256 + threadIdx.x;
        const int t = a.tgt[i];
        const bool b0 = (t >= CUT0) && (t < CUT1);
        const bool b1 = (t >= CUT1) && (t < CUT2);
        a.m0f[i] = b0 ? 1.0f : 0.0f;
        a.m1f[i] = b1 ? 1.0f : 0.0f;
        const int nt = b0 ? CUT0 : (b1 ? (CUT0 + 1) : t);
        a.outT[i] = (float)nt;
    }
    // ---- grid-stride over all cast segments (16B chunks) ----
    long i = blockIdx.x * 256L + threadIdx.x;
    const long stride = (long)gridDim.x * 256L;
    for (; i < a.grand8; i += stride) {
        long off = i;
        int s = 0;
        while (s < 4 && off >= a.s[s].total8) { off -= a.s[s].total8; s++; }
        const CastSeg& sg = a.s[s];
        const long e   = off << 3;
        const long row = e >> sg.lk;
        ushort8 o;
        const float* src = nullptr;
        long r2 = row;
        if (row < sg.rowsA)      src = sg.srcA;
        else if (row < sg.rowsB) { src = sg.srcB; r2 = row - sg.rowsA; }
        if (src) {
            const long col = e & ((1L << sg.lk) - 1);
            const float* p = src + (r2 << sg.lk) + col;
            const float4 v0 = *(const float4*)(p);
            const float4 v1 = *(const float4*)(p + 4);
            o[0] = f2bf(v0.x); o[1] = f2bf(v0.y); o[2] = f2bf(v0.z); o[3] = f2bf(v0.w);
            o[4] = f2bf(v1.x); o[5] = f2bf(v1.y); o[6] = f2bf(v1.z); o[7] = f2bf(v1.w);
        } else {
            o = (ushort8)0;
        }
        *(ushort8*)(sg.dst + e) = o;
    }
}

// ===========================================================================
// 8-phase 256x256 BK=64 GEMM (T2 swizzle + T3/T4 counted vmcnt + T5 setprio),
// dual-config: blocks [0, nblk0) = head (f32 out, ldc=LDC), blocks [nblk0, ..)
// = h01 hidden projection (bf16 out, ldc=ldc1).  NM = 16 for both.
// Swapped MFMA operands: D row field = B-row = output col (contiguous stores).
// ===========================================================================
#define STAGE2(MATP, LDM, RB, KCOL, LOFF)                                          \
    do {                                                                           \
        const unsigned short* _s0 = (MATP) + ((long)((RB) + (tid >> 3))) * (LDM) + (KCOL); \
        gload16(_s0, smem + (LOFF) + wave * 1024);                                 \
        const unsigned short* _s1 = (MATP) + ((long)((RB) + 64 + (tid >> 3))) * (LDM) + (KCOL); \
        gload16(_s1, smem + (LOFF) + 8192 + wave * 1024);                          \
    } while (0)

__global__ __launch_bounds__(512, 2)
void gemm8_dual_kernel(const unsigned short* __restrict__ A0,
                       const unsigned short* __restrict__ B0,
                       float* __restrict__ C0,
                       int nkt0, int lda0, int ldb0, int width0, int NB0, int nblk0,
                       const unsigned short* __restrict__ A1,
                       const unsigned short* __restrict__ B1,
                       unsigned short* __restrict__ C1,
                       int nkt1, int lda1, int ldb1, long ldc1, int width1, int NB1) {
    __shared__ char smem[131072];

    const int tid  = threadIdx.x;
    const int lane = tid & 63;
    const int wave = tid >> 6;
    const int wr   = wave >> 2;            // M half 0..1
    const int wc   = wave & 3;             // N quarter 0..3

    const bool isHead = (int)blockIdx.x < nblk0;
    const unsigned short* A = isHead ? A0 : A1;
    const unsigned short* B = isHead ? B0 : B1;
    const int nkt   = isHead ? nkt0 : nkt1;
    const int lda   = isHead ? lda0 : lda1;
    const int ldb   = isHead ? ldb0 : ldb1;
    const int width = isHead ? width0 : width1;
    const int NB    = isHead ? NB0 : NB1;
    const int lbid  = isHead ? blockIdx.x : blockIdx.x - nblk0;
    const int nwg   = isHead ? nblk0 : (int)gridDim.x - nblk0;

    // bijective XCD chunk + GROUP_M=4 (bm fastest); nwg % 8 == 0 always here
    const int q = nwg >> 3, r = nwg & 7;
    const int xcd = lbid & 7, loc = lbid >> 3;
    const int L = (xcd < r ? xcd * (q + 1) : r * (q + 1) + (xcd - r) * q) + loc;
    const int g = L / (NB * 4);
    const int t = L - g * (NB * 4);
    const long bm = g * 4 + (t & 3);
    const long bn = t >> 2;

    const long bmRow = bm * 256;
    const long bnRow = bn * 256;

    // staging source column (elems), pre-swizzled: ((tid&7)*8) ^ (((tid>>5)&1)<<4)
    const int scol = ((tid & 7) << 3) ^ (((tid >> 5) & 1) << 4);

    // ds_read per-lane address pieces
    const unsigned lane15 = lane & 15;
    const unsigned sw    = ((lane >> 2) & 1) << 5;
    const unsigned kcol0 = (((lane >> 4) << 4)) ^ sw;        // kk=0 byte col
    const unsigned kcol1 = (64u + ((lane >> 4) << 4)) ^ sw;  // kk=1 byte col
    const unsigned smemBase =
        (unsigned)(size_t)(__attribute__((address_space(3))) char*)smem;
    const unsigned aB0 = smemBase + wr * 16384 + lane15 * 128;
    const unsigned bB0 = smemBase + 32768 + (wc >> 1) * 16384 +
                         ((wc & 1) * 64 + lane15) * 128;

    f32x4 acc[8][4];
#pragma unroll
    for (int m = 0; m < 8; m++)
#pragma unroll
        for (int n = 0; n < 4; n++) acc[m][n] = (f32x4){0.f, 0.f, 0.f, 0.f};

    // ---- prologue: stage K-tile 0 into buf 0 (8 loads/thread) ----
    STAGE2(A, lda, bmRow,       scol, 0);
    STAGE2(A, lda, bmRow + 128, scol, 16384);
    STAGE2(B, ldb, bnRow,       scol, 32768);
    STAGE2(B, ldb, bnRow + 128, scol, 49152);

    short8 afk0[4], afk1[4], bA0[2], bA1[2], bH0[2], bH1[2];

    for (int kt = 0; kt < nkt; ++kt) {
        const int c  = kt & 1;
        const bool pf = (kt + 1) < nkt;
        const int kc = (kt + 1) * 64 + scol;
        const unsigned aBase = aB0 + c * 65536;
        const unsigned bBase = bB0 + c * 65536;
        const unsigned lOff  = (c ^ 1) * 65536;

        // -------- phase 0 : Q0 = (mLo, nLo) --------
        if (pf) {
            STAGE2(A, lda, bmRow, kc, lOff);
            asm volatile("s_waitcnt vmcnt(2)" ::: "memory");
        } else {
            asm volatile("s_waitcnt vmcnt(0)" ::: "memory");
        }
        __builtin_amdgcn_s_barrier();
#pragma unroll
        for (int mf = 0; mf < 4; ++mf) {
            afk0[mf] = dsr128(aBase + mf * 2048 + kcol0);
            afk1[mf] = dsr128(aBase + mf * 2048 + kcol1);
        }
#pragma unroll
        for (int nf = 0; nf < 2; ++nf) {
            bA0[nf] = dsr128(bBase + nf * 2048 + kcol0);
            bA1[nf] = dsr128(bBase + nf * 2048 + kcol1);
        }
        asm volatile("s_waitcnt lgkmcnt(0)" ::: "memory");
        __builtin_amdgcn_sched_barrier(0);
        __builtin_amdgcn_s_setprio(1);
#pragma unroll
        for (int mf = 0; mf < 4; ++mf)
#pragma unroll
            for (int nf = 0; nf < 2; ++nf) {
                acc[mf][nf] = mfma16(bA0[nf], afk0[mf], acc[mf][nf]);
                acc[mf][nf] = mfma16(bA1[nf], afk1[mf], acc[mf][nf]);
            }
        __builtin_amdgcn_s_setprio(0);
        __builtin_amdgcn_s_barrier();

        // -------- phase 1 : Q1 = (mLo, nHi) --------
#pragma unroll
        for (int nf = 0; nf < 2; ++nf) {
            bH0[nf] = dsr128(bBase + (2 + nf) * 2048 + kcol0);
            bH1[nf] = dsr128(bBase + (2 + nf) * 2048 + kcol1);
        }
        if (pf) STAGE2(A, lda, bmRow + 128, kc, lOff + 16384);
        __builtin_amdgcn_s_barrier();
        asm volatile("s_waitcnt lgkmcnt(0)" ::: "memory");
        __builtin_amdgcn_sched_barrier(0);
        __builtin_amdgcn_s_setprio(1);
#pragma unroll
        for (int mf = 0; mf < 4; ++mf)
#pragma unroll
            for (int nf = 0; nf < 2; ++nf) {
                acc[mf][2 + nf] = mfma16(bH0[nf], afk0[mf], acc[mf][2 + nf]);
                acc[mf][2 + nf] = mfma16(bH1[nf], afk1[mf], acc[mf][2 + nf]);
            }
        __builtin_amdgcn_s_setprio(0);
        __builtin_amdgcn_s_barrier();

        // -------- phase 2 : Q2 = (mHi, nHi) --------
#pragma unroll
        for (int mf = 0; mf < 4; ++mf) {
            afk0[mf] = dsr128(aBase + (4 + mf) * 2048 + kcol0);
            afk1[mf] = dsr128(aBase + (4 + mf) * 2048 + kcol1);
        }
        if (pf) STAGE2(B, ldb, bnRow, kc, lOff + 32768);
        __builtin_amdgcn_s_barrier();
        asm volatile("s_waitcnt lgkmcnt(0)" ::: "memory");
        __builtin_amdgcn_sched_barrier(0);
        __builtin_amdgcn_s_setprio(1);
#pragma unroll
        for (int mf = 0; mf < 4; ++mf)
#pragma unroll
            for (int nf = 0; nf < 2; ++nf) {
                acc[4 + mf][2 + nf] = mfma16(bH0[nf], afk0[mf], acc[4 + mf][2 + nf]);
                acc[4 + mf][2 + nf] = mfma16(bH1[nf], afk1[mf], acc[4 + mf][2 + nf]);
            }
        __builtin_amdgcn_s_setprio(0);
        __builtin_amdgcn_s_barrier();

        // -------- phase 3 : Q3 = (mHi, nLo) --------
#pragma unroll
        for (int nf = 0; nf < 2; ++nf) {
            bA0[nf] = dsr128(bBase + nf * 2048 + kcol0);
            bA1[nf] = dsr128(bBase + nf * 2048 + kcol1);
        }
        if (pf) STAGE2(B, ldb, bnRow + 128, kc, lOff + 49152);
        __builtin_amdgcn_s_barrier();
        asm volatile("s_waitcnt lgkmcnt(0)" ::: "memory");
        __builtin_amdgcn_sched_barrier(0);
        __builtin_amdgcn_s_setprio(1);
#pragma unroll
        for (int mf = 0; mf < 4; ++mf)
#pragma unroll
            for (int nf = 0; nf < 2; ++nf) {
                acc[4 + mf][nf] = mfma16(bA0[nf], afk0[mf], acc[4 + mf][nf]);
                acc[4 + mf][nf] = mfma16(bA1[nf], afk1[mf], acc[4 + mf][nf]);
            }
        __builtin_amdgcn_s_setprio(0);
        __builtin_amdgcn_s_barrier();
    }

    // ---- epilogue: lane holds rows (lane&15), 4 consecutive cols ((lane>>4)*4)
    const int cb4 = (lane >> 4) << 2;
    if (isHead) {
#pragma unroll
        for (int mf = 0; mf < 8; ++mf) {
            const long grow = bmRow + wr * 128 + mf * 16 + lane15;
            float* rp = C0 + grow * LDC;
#pragma unroll
            for (int nf = 0; nf < 4; ++nf) {
                const int gcb = (int)bnRow + wc * 64 + nf * 16 + cb4;
                f32x4 v = acc[mf][nf];
                if (gcb + 3 < width) {
                    __builtin_memcpy(rp + gcb, &v, 16);   // ldc odd -> 4B-aligned
                } else {
#pragma unroll
                    for (int j = 0; j < 4; ++j)
                        if (gcb + j < width) rp[gcb + j] = v[j];
                }
            }
        }
    } else {
#pragma unroll
        for (int mf = 0; mf < 8; ++mf) {
            const long grow = bmRow + wr * 128 + mf * 16 + lane15;
            unsigned short* rp = C1 + grow * ldc1;
#pragma unroll
            for (int nf = 0; nf < 4; ++nf) {
                const int gcb = (int)bnRow + wc * 64 + nf * 16 + cb4;
                const f32x4 v = acc[mf][nf];
                ushort4 o;
                o.x = f2bf(v[0]); o.y = f2bf(v[1]); o.z = f2bf(v[2]); o.w = f2bf(v[3]);
                if (gcb + 3 < width) {
                    *(ushort4*)(rp + gcb) = o;            // ldc1 even -> 8B-aligned
                } else {
                    unsigned short tmp[4] = {o.x, o.y, o.z, o.w};
#pragma unroll
                    for (int j = 0; j < 4; ++j)
                        if (gcb + j < width) rp[gcb + j] = tmp[j];
                }
            }
        }
    }
}

// ===========================================================================
// m97-structure 128x128 GEMM, dual-config: blocks [0, nblk0) = tail0, rest =
// tail1. f32 out with row mask. ~3 blocks/CU -> epilogue stores of one block
// overlap the next block's MFMA. Swapped operands (contiguous col stores).
// ===========================================================================
__global__ __launch_bounds__(256)
void gemm_tails_kernel(const unsigned short* __restrict__ A0,
                       const unsigned short* __restrict__ B0,
                       float* __restrict__ C0,
                       const float* __restrict__ mask0,
                       int K0, int lda0, int width0, int NB0, int nblk0,
                       const unsigned short* __restrict__ A1,
                       const unsigned short* __restrict__ B1,
                       float* __restrict__ C1,
                       const float* __restrict__ mask1,
                       int K1, int lda1, int width1, int NB1) {
    __shared__ unsigned short As[128 * 32];
    __shared__ unsigned short Bs[128 * 32];

    const int tid  = threadIdx.x;
    const int lane = tid & 63;
    const int wave = tid >> 6;
    const int wr   = wave >> 1;
    const int wc   = wave & 1;

    const bool is0 = (int)blockIdx.x < nblk0;
    const unsigned short* A = is0 ? A0 : A1;
    const unsigned short* B = is0 ? B0 : B1;
    float* Cf               = is0 ? C0 : C1;
    const float* rowMask    = is0 ? mask0 : mask1;
    const int K     = is0 ? K0 : K1;
    const int lda   = is0 ? lda0 : lda1;
    const int width = is0 ? width0 : width1;
    const int NB    = is0 ? NB0 : NB1;
    const int lbid  = is0 ? blockIdx.x : blockIdx.x - nblk0;
    const int nwg   = is0 ? nblk0 : (int)gridDim.x - nblk0;

    // bijective XCD chunk + GROUP_M=8 (bm fastest); nwg % 8 == 0 here
    const int q = nwg >> 3, r = nwg & 7;
    const int xcd = lbid & 7, loc = lbid >> 3;
    const int L = (xcd < r ? xcd * (q + 1) : r * (q + 1) + (xcd - r) * q) + loc;
    const int g = L / (NB << 3);
    const int t = L - g * (NB << 3);
    const long bm = (g << 3) + (t & 7);
    const long bn = t >> 3;

    const int s_row = tid >> 2;
    const int s_col = (tid & 3) << 3;

    const unsigned short* pA = A + (bm * 128 + s_row) * (long)lda + s_col;
    const unsigned short* pB = B + (bn * 128 + s_row) * (long)K + s_col;

    char* asb = (char*)As + wave * 1024;
    char* bsb = (char*)Bs + wave * 1024;

    f32x4 acc[4][4];
#pragma unroll
    for (int m = 0; m < 4; m++)
#pragma unroll
        for (int n = 0; n < 4; n++) acc[m][n] = (f32x4){0.f, 0.f, 0.f, 0.f};

    const int f_r = lane & 15;
    const int f_k = (lane >> 4) << 3;

    for (int k0 = 0; k0 < K; k0 += 32) {
        gload16(pA + k0,             asb);
        gload16(pA + k0 + 64L * lda, asb + 4096);
        gload16(pB + k0,             bsb);
        gload16(pB + k0 + 64L * K,   bsb + 4096);
        __syncthreads();

        short8 af[4], bfr[4];
#pragma unroll
        for (int m = 0; m < 4; m++)
            af[m] = *(const short8*)&As[(wr * 64 + m * 16 + f_r) * 32 + f_k];
#pragma unroll
        for (int n = 0; n < 4; n++)
            bfr[n] = *(const short8*)&Bs[(wc * 64 + n * 16 + f_r) * 32 + f_k];

#pragma unroll
        for (int m = 0; m < 4; m++)
#pragma unroll
            for (int n = 0; n < 4; n++)
                acc[m][n] = __builtin_amdgcn_mfma_f32_16x16x32_bf16(
                    bfr[n], af[m], acc[m][n], 0, 0, 0);
        __syncthreads();
    }

    const int c_a  = lane & 15;
    const int c_b4 = (lane >> 4) << 2;
#pragma unroll
    for (int m = 0; m < 4; m++) {
        const long grow = bm * 128 + wr * 64 + m * 16 + c_a;
        float* rp = Cf + grow * LDC;
        const float msk = rowMask[grow];
#pragma unroll
        for (int n = 0; n < 4; n++) {
            const int gcb = (int)(bn * 128) + wc * 64 + n * 16 + c_b4;
            f32x4 v = acc[m][n];
            v[0] *= msk; v[1] *= msk; v[2] *= msk; v[3] *= msk;
            if (gcb + 3 < width) {
                __builtin_memcpy(rp + gcb, &v, 16);   // LDC odd -> 4B-aligned
            } else {
#pragma unroll
                for (int j = 0; j < 4; j++)
                    if (gcb + j < width) rp[gcb + j] = v[j];
            }
        }
    }
}

extern "C" void kernel_launch(void* const* d_in, const int* in_sizes, int n_in,
                              void* d_out, int out_size, void* d_ws, size_t ws_size,
                              hipStream_t stream) {
    const float* x      = (const float*)d_in[0];   // [4096,1024]
    const int*   target = (const int*)  d_in[1];   // [4096]
    const float* head_w = (const float*)d_in[2];   // [10002,1024]
    const float* t0_w1  = (const float*)d_in[3];   // [256,1024]
    const float* t0_w2  = (const float*)d_in[4];   // [30000,256]
    const float* t1_w1  = (const float*)d_in[5];   // [64,1024]
    const float* t1_w2  = (const float*)d_in[6];   // [10257,64]
    float* out = (float*)d_out;

    // ---- ws layout (bytes) ----
    char* ws = (char*)d_ws;
    unsigned short* xb    = (unsigned short*)(ws + 0);          // 4096x1024
    unsigned short* hwb   = (unsigned short*)(ws + 8388608);    // 10240x1024
    unsigned short* w01b  = (unsigned short*)(ws + 29360128);   // 512x1024 (t0w1|t1w1|0)
    unsigned short* t0w2b = (unsigned short*)(ws + 30408704);   // 30208x256
    unsigned short* t1w2b = (unsigned short*)(ws + 45875200);   // 10496x64
    unsigned short* h01   = (unsigned short*)(ws + 47218688);   // 4096x384 bf16
    float*          m0f   = (float*)        (ws + 50364416);    // 4096
    float*          m1f   = (float*)        (ws + 50380800);    // 4096

    // ---- launch 1: fused casts + target/masks ----
    CastArgs ca;
    ca.s[0] = {x,      nullptr, xb,    4096,  4096,  524288,  10, 0};
    ca.s[1] = {head_w, nullptr, hwb,   10002, 10002, 1310720, 10, 0};
    ca.s[2] = {t0_w1,  t1_w1,   w01b,  256,   320,   65536,   10, 0};
    ca.s[3] = {t0_w2,  nullptr, t0w2b, 30000, 30000, 966656,  8,  0};
    ca.s[4] = {t1_w2,  nullptr, t1w2b, 10257, 10257, 83968,   6,  0};
    ca.grand8 = 524288 + 1310720 + 65536 + 966656 + 83968;  // 2951168
    ca.tgt = target;
    ca.outT = out + 4096L * LDC;
    ca.m0f = m0f;
    ca.m1f = m1f;
    cast_all_kernel<<<2048, 256, 0, stream>>>(ca);

    // ---- launch 2: head (640 blocks, 8-phase) + h01 (32 blocks) ----
    //   head: out[:,0:10002] = x @ head_w^T   (NM=16, NB=40, nkt=16)
    //   h01:  h01[4096,384] = bf16(x @ [t0w1;t1w1;0]^T)  (NM=16, NB=2, nkt=16)
    gemm8_dual_kernel<<<dim3(672), 512, 0, stream>>>(
        xb, hwb, out, 16, 1024, 1024, 10002, 40, 640,
        xb, w01b, h01, 16, 1024, 1024, 384L, 384, 2);

    // ---- launch 3: tail0 (7520 blocks) + tail1 (2592 blocks), m97-128^2 ----
    //   tail0: out[:,10002:40002] = (h0 @ t0w2^T) * m0   (NB=235, K=256)
    //   tail1: out[:,40002:50259] = (h1 @ t1w2^T) * m1   (NB=81,  K=64)
    gemm_tails_kernel<<<dim3(10112), 256, 0, stream>>>(
        h01,       t0w2b, out + 10002, m0f, 256, 384, 30000, 235, 7520,
        h01 + 256, t1w2b, out + 40002, m1f, 64,  384, 10257, 81);
}

// Round 5
// 410.371 us; speedup vs baseline: 1.4276x; 1.0214x over previous
//
#include <hip/hip_runtime.h>
#include <hip/hip_bf16.h>
#include <stdint.h>

// ---------------------------------------------------------------------------
// FacebookAdaptiveSoftmax forward on MI355X (gfx950) — R5
//   out[4096, 50259] = concat(x@head_w^T, (x@t0w1^T)@t0w2^T * m0, (x@t1w1^T)@t1w2^T * m1)
//   new_head_target[4096] appended flat (as float)
// R5: 4 launches.
//   L0: 1-block scan -> new_head_target, compacted in-bucket row lists +
//       zero-row lists + counts (order-preserving, deterministic).
//   L1: fused casts + zero-fill of masked tail rows (write BW overlaps reads).
//   L2: head (8-phase 256^2) + h01 dual GEMM (R4-verified).
//   L3: compacted tail GEMMs (gather A-rows, scatter C-rows, early-exit
//       beyond ceil(cnt/128) row-tiles). No mask multiply needed.
// ---------------------------------------------------------------------------

typedef float  f32x4   __attribute__((ext_vector_type(4)));
typedef short  short8  __attribute__((ext_vector_type(8)));
typedef unsigned short ushort8 __attribute__((ext_vector_type(8)));

#define CUT0 10000
#define CUT1 40000
#define CUT2 50257
#define LDC   50259L

__device__ __forceinline__ void gload16(const void* g, void* l) {
    __builtin_amdgcn_global_load_lds(
        (__attribute__((address_space(1))) void*)(g),
        (__attribute__((address_space(3))) void*)(l), 16, 0, 0);
}

__device__ __forceinline__ unsigned short f2bf(float f) {
    unsigned int u = __float_as_uint(f);
    u += 0x7fffu + ((u >> 16) & 1u);   // round-to-nearest-even
    return (unsigned short)(u >> 16);
}

__device__ __forceinline__ short8 dsr128(unsigned addr) {
    f32x4 r;
    asm volatile("ds_read_b128 %0, %1" : "=v"(r) : "v"(addr));
    return __builtin_bit_cast(short8, r);
}

__device__ __forceinline__ f32x4 mfma16(short8 a, short8 b, f32x4 c) {
    return __builtin_amdgcn_mfma_f32_16x16x32_bf16(a, b, c, 0, 0, 0);
}

// ===========================================================================
// L0: target remap + order-preserving compaction scan (1 block, 1024 thr).
//   in0[cnt0]  = rows with target in [CUT0,CUT1)      (ascending)
//   z0[4096-cnt0] = rows NOT in bucket0               (ascending)
//   in1/z1 likewise for [CUT1,CUT2); cnts[0]=cnt0, cnts[1]=cnt1.
// ===========================================================================
__global__ __launch_bounds__(1024)
void scan_kernel(const int* __restrict__ tgt, float* __restrict__ outT,
                 int* __restrict__ in0, int* __restrict__ z0,
                 int* __restrict__ in1, int* __restrict__ z1,
                 int* __restrict__ cnts) {
    __shared__ int w0[16], w1[16];
    const int t = threadIdx.x;
    int f0[4], f1[4];
    int c0 = 0, c1 = 0;
#pragma unroll
    for (int j = 0; j < 4; ++j) {
        const int r = t * 4 + j;
        const int v = tgt[r];
        const int b0 = (v >= CUT0) && (v < CUT1);
        const int b1 = (v >= CUT1) && (v < CUT2);
        f0[j] = b0; f1[j] = b1;
        c0 += b0; c1 += b1;
        outT[r] = (float)(b0 ? CUT0 : (b1 ? CUT0 + 1 : v));
    }
    const int lane = t & 63, w = t >> 6;
    int s0 = c0, s1 = c1;
    for (int d = 1; d < 64; d <<= 1) {
        const int u0 = __shfl_up(s0, d, 64);
        const int u1 = __shfl_up(s1, d, 64);
        if (lane >= d) { s0 += u0; s1 += u1; }
    }
    if (lane == 63) { w0[w] = s0; w1[w] = s1; }
    __syncthreads();
    if (t == 0) {
        int a0 = 0, a1 = 0;
        for (int i = 0; i < 16; ++i) {
            const int x0 = w0[i]; w0[i] = a0; a0 += x0;
            const int x1 = w1[i]; w1[i] = a1; a1 += x1;
        }
        cnts[0] = a0; cnts[1] = a1;
    }
    __syncthreads();
    int run0 = w0[w] + (s0 - c0);   // exclusive in-bucket prefix at row t*4
    int run1 = w1[w] + (s1 - c1);
#pragma unroll
    for (int j = 0; j < 4; ++j) {
        const int r = t * 4 + j;
        if (f0[j]) in0[run0++] = r; else z0[r - run0] = r;
        if (f1[j]) in1[run1++] = r; else z1[r - run1] = r;
    }
}

// ===========================================================================
// L1: fused cast (5 segments) + zero-fill of masked tail rows.
// Blocks [0,4096): tail0 zero rows; [4096,8192): tail1 zero rows;
// [8192, 8192+2048): grid-stride casts.
// ===========================================================================
struct CastSeg {
    const float* srcA;
    const float* srcB;
    unsigned short* dst;
    long rowsA, rowsB, total8;
    int lk, pad;
};
struct CastArgs {
    CastSeg s[5];
    long grand8;
    const int* z0;
    const int* z1;
    const int* cnts;
    float* out;
};

__global__ __launch_bounds__(256)
void cast_fill_kernel(CastArgs a) {
    const int b = blockIdx.x;
    if (b < 8192) {
        const bool t0 = b < 4096;
        const int i = t0 ? b : b - 4096;
        const int zc = 4096 - a.cnts[t0 ? 0 : 1];
        if (i < zc) {
            const int r = (t0 ? a.z0 : a.z1)[i];
            float* base = a.out + (long)r * LDC + (t0 ? 10002 : 40002);
            const int n = t0 ? 30000 : 10257;
            const f32x4 zv = {0.f, 0.f, 0.f, 0.f};
            for (int j = (int)threadIdx.x * 4; j <= n - 4; j += 1024)
                __builtin_memcpy(base + j, &zv, 16);   // 4B-aligned ok
            for (int j = (n & ~3) + (int)threadIdx.x; j < n; j += 256)
                base[j] = 0.f;
        }
        return;
    }
    long i = (b - 8192) * 256L + threadIdx.x;
    const long stride = ((long)gridDim.x - 8192) * 256L;
    for (; i < a.grand8; i += stride) {
        long off = i;
        int s = 0;
        while (s < 4 && off >= a.s[s].total8) { off -= a.s[s].total8; s++; }
        const CastSeg& sg = a.s[s];
        const long e   = off << 3;
        const long row = e >> sg.lk;
        ushort8 o;
        const float* src = nullptr;
        long r2 = row;
        if (row < sg.rowsA)      src = sg.srcA;
        else if (row < sg.rowsB) { src = sg.srcB; r2 = row - sg.rowsA; }
        if (src) {
            const long col = e & ((1L << sg.lk) - 1);
            const float* p = src + (r2 << sg.lk) + col;
            const float4 v0 = *(const float4*)(p);
            const float4 v1 = *(const float4*)(p + 4);
            o[0] = f2bf(v0.x); o[1] = f2bf(v0.y); o[2] = f2bf(v0.z); o[3] = f2bf(v0.w);
            o[4] = f2bf(v1.x); o[5] = f2bf(v1.y); o[6] = f2bf(v1.z); o[7] = f2bf(v1.w);
        } else {
            o = (ushort8)0;
        }
        *(ushort8*)(sg.dst + e) = o;
    }
}

// ===========================================================================
// L2: 8-phase 256x256 BK=64 GEMM, dual-config (head f32-out | h01 bf16-out).
// Unchanged from R4 (verified).
// ===========================================================================
#define STAGE2(MATP, LDM, RB, KCOL, LOFF)                                          \
    do {                                                                           \
        const unsigned short* _s0 = (MATP) + ((long)((RB) + (tid >> 3))) * (LDM) + (KCOL); \
        gload16(_s0, smem + (LOFF) + wave * 1024);                                 \
        const unsigned short* _s1 = (MATP) + ((long)((RB) + 64 + (tid >> 3))) * (LDM) + (KCOL); \
        gload16(_s1, smem + (LOFF) + 8192 + wave * 1024);                          \
    } while (0)

__global__ __launch_bounds__(512, 2)
void gemm8_dual_kernel(const unsigned short* __restrict__ A0,
                       const unsigned short* __restrict__ B0,
                       float* __restrict__ C0,
                       int nkt0, int lda0, int ldb0, int width0, int NB0, int nblk0,
                       const unsigned short* __restrict__ A1,
                       const unsigned short* __restrict__ B1,
                       unsigned short* __restrict__ C1,
                       int nkt1, int lda1, int ldb1, long ldc1, int width1, int NB1) {
    __shared__ char smem[131072];

    const int tid  = threadIdx.x;
    const int lane = tid & 63;
    const int wave = tid >> 6;
    const int wr   = wave >> 2;
    const int wc   = wave & 3;

    const bool isHead = (int)blockIdx.x < nblk0;
    const unsigned short* A = isHead ? A0 : A1;
    const unsigned short* B = isHead ? B0 : B1;
    const int nkt   = isHead ? nkt0 : nkt1;
    const int lda   = isHead ? lda0 : lda1;
    const int ldb   = isHead ? ldb0 : ldb1;
    const int width = isHead ? width0 : width1;
    const int NB    = isHead ? NB0 : NB1;
    const int lbid  = isHead ? blockIdx.x : blockIdx.x - nblk0;
    const int nwg   = isHead ? nblk0 : (int)gridDim.x - nblk0;

    const int q = nwg >> 3, r = nwg & 7;
    const int xcd = lbid & 7, loc = lbid >> 3;
    const int L = (xcd < r ? xcd * (q + 1) : r * (q + 1) + (xcd - r) * q) + loc;
    const int g = L / (NB * 4);
    const int t = L - g * (NB * 4);
    const long bm = g * 4 + (t & 3);
    const long bn = t >> 2;

    const long bmRow = bm * 256;
    const long bnRow = bn * 256;

    const int scol = ((tid & 7) << 3) ^ (((tid >> 5) & 1) << 4);

    const unsigned lane15 = lane & 15;
    const unsigned sw    = ((lane >> 2) & 1) << 5;
    const unsigned kcol0 = (((lane >> 4) << 4)) ^ sw;
    const unsigned kcol1 = (64u + ((lane >> 4) << 4)) ^ sw;
    const unsigned smemBase =
        (unsigned)(size_t)(__attribute__((address_space(3))) char*)smem;
    const unsigned aB0 = smemBase + wr * 16384 + lane15 * 128;
    const unsigned bB0 = smemBase + 32768 + (wc >> 1) * 16384 +
                         ((wc & 1) * 64 + lane15) * 128;

    f32x4 acc[8][4];
#pragma unroll
    for (int m = 0; m < 8; m++)
#pragma unroll
        for (int n = 0; n < 4; n++) acc[m][n] = (f32x4){0.f, 0.f, 0.f, 0.f};

    STAGE2(A, lda, bmRow,       scol, 0);
    STAGE2(A, lda, bmRow + 128, scol, 16384);
    STAGE2(B, ldb, bnRow,       scol, 32768);
    STAGE2(B, ldb, bnRow + 128, scol, 49152);

    short8 afk0[4], afk1[4], bA0[2], bA1[2], bH0[2], bH1[2];

    for (int kt = 0; kt < nkt; ++kt) {
        const int c  = kt & 1;
        const bool pf = (kt + 1) < nkt;
        const int kc = (kt + 1) * 64 + scol;
        const unsigned aBase = aB0 + c * 65536;
        const unsigned bBase = bB0 + c * 65536;
        const unsigned lOff  = (c ^ 1) * 65536;

        // phase 0 : Q0
        if (pf) {
            STAGE2(A, lda, bmRow, kc, lOff);
            asm volatile("s_waitcnt vmcnt(2)" ::: "memory");
        } else {
            asm volatile("s_waitcnt vmcnt(0)" ::: "memory");
        }
        __builtin_amdgcn_s_barrier();
#pragma unroll
        for (int mf = 0; mf < 4; ++mf) {
            afk0[mf] = dsr128(aBase + mf * 2048 + kcol0);
            afk1[mf] = dsr128(aBase + mf * 2048 + kcol1);
        }
#pragma unroll
        for (int nf = 0; nf < 2; ++nf) {
            bA0[nf] = dsr128(bBase + nf * 2048 + kcol0);
            bA1[nf] = dsr128(bBase + nf * 2048 + kcol1);
        }
        asm volatile("s_waitcnt lgkmcnt(0)" ::: "memory");
        __builtin_amdgcn_sched_barrier(0);
        __builtin_amdgcn_s_setprio(1);
#pragma unroll
        for (int mf = 0; mf < 4; ++mf)
#pragma unroll
            for (int nf = 0; nf < 2; ++nf) {
                acc[mf][nf] = mfma16(bA0[nf], afk0[mf], acc[mf][nf]);
                acc[mf][nf] = mfma16(bA1[nf], afk1[mf], acc[mf][nf]);
            }
        __builtin_amdgcn_s_setprio(0);
        __builtin_amdgcn_s_barrier();

        // phase 1 : Q1
#pragma unroll
        for (int nf = 0; nf < 2; ++nf) {
            bH0[nf] = dsr128(bBase + (2 + nf) * 2048 + kcol0);
            bH1[nf] = dsr128(bBase + (2 + nf) * 2048 + kcol1);
        }
        if (pf) STAGE2(A, lda, bmRow + 128, kc, lOff + 16384);
        __builtin_amdgcn_s_barrier();
        asm volatile("s_waitcnt lgkmcnt(0)" ::: "memory");
        __builtin_amdgcn_sched_barrier(0);
        __builtin_amdgcn_s_setprio(1);
#pragma unroll
        for (int mf = 0; mf < 4; ++mf)
#pragma unroll
            for (int nf = 0; nf < 2; ++nf) {
                acc[mf][2 + nf] = mfma16(bH0[nf], afk0[mf], acc[mf][2 + nf]);
                acc[mf][2 + nf] = mfma16(bH1[nf], afk1[mf], acc[mf][2 + nf]);
            }
        __builtin_amdgcn_s_setprio(0);
        __builtin_amdgcn_s_barrier();

        // phase 2 : Q2
#pragma unroll
        for (int mf = 0; mf < 4; ++mf) {
            afk0[mf] = dsr128(aBase + (4 + mf) * 2048 + kcol0);
            afk1[mf] = dsr128(aBase + (4 + mf) * 2048 + kcol1);
        }
        if (pf) STAGE2(B, ldb, bnRow, kc, lOff + 32768);
        __builtin_amdgcn_s_barrier();
        asm volatile("s_waitcnt lgkmcnt(0)" ::: "memory");
        __builtin_amdgcn_sched_barrier(0);
        __builtin_amdgcn_s_setprio(1);
#pragma unroll
        for (int mf = 0; mf < 4; ++mf)
#pragma unroll
            for (int nf = 0; nf < 2; ++nf) {
                acc[4 + mf][2 + nf] = mfma16(bH0[nf], afk0[mf], acc[4 + mf][2 + nf]);
                acc[4 + mf][2 + nf] = mfma16(bH1[nf], afk1[mf], acc[4 + mf][2 + nf]);
            }
        __builtin_amdgcn_s_setprio(0);
        __builtin_amdgcn_s_barrier();

        // phase 3 : Q3
#pragma unroll
        for (int nf = 0; nf < 2; ++nf) {
            bA0[nf] = dsr128(bBase + nf * 2048 + kcol0);
            bA1[nf] = dsr128(bBase + nf * 2048 + kcol1);
        }
        if (pf) STAGE2(B, ldb, bnRow + 128, kc, lOff + 49152);
        __builtin_amdgcn_s_barrier();
        asm volatile("s_waitcnt lgkmcnt(0)" ::: "memory");
        __builtin_amdgcn_sched_barrier(0);
        __builtin_amdgcn_s_setprio(1);
#pragma unroll
        for (int mf = 0; mf < 4; ++mf)
#pragma unroll
            for (int nf = 0; nf < 2; ++nf) {
                acc[4 + mf][nf] = mfma16(bA0[nf], afk0[mf], acc[4 + mf][nf]);
                acc[4 + mf][nf] = mfma16(bA1[nf], afk1[mf], acc[4 + mf][nf]);
            }
        __builtin_amdgcn_s_setprio(0);
        __builtin_amdgcn_s_barrier();
    }

    const int cb4 = (lane >> 4) << 2;
    if (isHead) {
#pragma unroll
        for (int mf = 0; mf < 8; ++mf) {
            const long grow = bmRow + wr * 128 + mf * 16 + lane15;
            float* rp = C0 + grow * LDC;
#pragma unroll
            for (int nf = 0; nf < 4; ++nf) {
                const int gcb = (int)bnRow + wc * 64 + nf * 16 + cb4;
                f32x4 v = acc[mf][nf];
                if (gcb + 3 < width) {
                    __builtin_memcpy(rp + gcb, &v, 16);
                } else {
#pragma unroll
                    for (int j = 0; j < 4; ++j)
                        if (gcb + j < width) rp[gcb + j] = v[j];
                }
            }
        }
    } else {
#pragma unroll
        for (int mf = 0; mf < 8; ++mf) {
            const long grow = bmRow + wr * 128 + mf * 16 + lane15;
            unsigned short* rp = C1 + grow * ldc1;
#pragma unroll
            for (int nf = 0; nf < 4; ++nf) {
                const int gcb = (int)bnRow + wc * 64 + nf * 16 + cb4;
                const f32x4 v = acc[mf][nf];
                ushort4 o;
                o.x = f2bf(v[0]); o.y = f2bf(v[1]); o.z = f2bf(v[2]); o.w = f2bf(v[3]);
                if (gcb + 3 < width) {
                    *(ushort4*)(rp + gcb) = o;
                } else {
                    unsigned short tmp[4] = {o.x, o.y, o.z, o.w};
#pragma unroll
                    for (int j = 0; j < 4; ++j)
                        if (gcb + j < width) rp[gcb + j] = tmp[j];
                }
            }
        }
    }
}

// ===========================================================================
// L3: compacted tails, m97-128^2 dual-config. Gather A rows via rowlist,
// scatter C rows; blocks with bm*128 >= cnt exit early.
// ===========================================================================
__global__ __launch_bounds__(256)
void gemm_tails_kernel(const unsigned short* __restrict__ A0,
                       const unsigned short* __restrict__ B0,
                       float* __restrict__ C0,
                       int K0, int lda0, int width0, int NB0, int nblk0,
                       const unsigned short* __restrict__ A1,
                       const unsigned short* __restrict__ B1,
                       float* __restrict__ C1,
                       int K1, int lda1, int width1, int NB1,
                       const int* __restrict__ in0,
                       const int* __restrict__ in1,
                       const int* __restrict__ cnts) {
    __shared__ unsigned short As[128 * 32];
    __shared__ unsigned short Bs[128 * 32];

    const int tid  = threadIdx.x;
    const int lane = tid & 63;
    const int wave = tid >> 6;
    const int wr   = wave >> 1;
    const int wc   = wave & 1;

    const bool is0 = (int)blockIdx.x < nblk0;
    const unsigned short* A = is0 ? A0 : A1;
    const unsigned short* B = is0 ? B0 : B1;
    float* Cf               = is0 ? C0 : C1;
    const int* rowlist      = is0 ? in0 : in1;
    const int cnt           = cnts[is0 ? 0 : 1];
    const int K     = is0 ? K0 : K1;
    const int lda   = is0 ? lda0 : lda1;
    const int width = is0 ? width0 : width1;
    const int NB    = is0 ? NB0 : NB1;
    const int lbid  = is0 ? blockIdx.x : blockIdx.x - nblk0;
    const int nwg   = is0 ? nblk0 : (int)gridDim.x - nblk0;

    const int q = nwg >> 3, r = nwg & 7;
    const int xcd = lbid & 7, loc = lbid >> 3;
    const int L = (xcd < r ? xcd * (q + 1) : r * (q + 1) + (xcd - r) * q) + loc;
    const int g = L / (NB << 3);
    const int t = L - g * (NB << 3);
    const long bm = (g << 3) + (t & 7);
    const long bn = t >> 3;

    if ((int)(bm * 128) >= cnt) return;   // inactive row-tile (uniform exit)

    const int cm1 = cnt - 1;
    const int s_row = tid >> 2;
    const int s_col = (tid & 3) << 3;
    const int gi0 = (int)(bm * 128) + s_row;
    const int gi1 = gi0 + 64;
    const int r0 = rowlist[gi0 < cnt ? gi0 : cm1];
    const int r1 = rowlist[gi1 < cnt ? gi1 : cm1];

    const unsigned short* pA0 = A + (long)r0 * lda + s_col;
    const unsigned short* pA1 = A + (long)r1 * lda + s_col;
    const unsigned short* pB  = B + (bn * 128 + s_row) * (long)K + s_col;

    char* asb = (char*)As + wave * 1024;
    char* bsb = (char*)Bs + wave * 1024;

    f32x4 acc[4][4];
#pragma unroll
    for (int m = 0; m < 4; m++)
#pragma unroll
        for (int n = 0; n < 4; n++) acc[m][n] = (f32x4){0.f, 0.f, 0.f, 0.f};

    const int f_r = lane & 15;
    const int f_k = (lane >> 4) << 3;

    for (int k0 = 0; k0 < K; k0 += 32) {
        gload16(pA0 + k0,          asb);
        gload16(pA1 + k0,          asb + 4096);
        gload16(pB + k0,           bsb);
        gload16(pB + k0 + 64L * K, bsb + 4096);
        __syncthreads();

        short8 af[4], bfr[4];
#pragma unroll
        for (int m = 0; m < 4; m++)
            af[m] = *(const short8*)&As[(wr * 64 + m * 16 + f_r) * 32 + f_k];
#pragma unroll
        for (int n = 0; n < 4; n++)
            bfr[n] = *(const short8*)&Bs[(wc * 64 + n * 16 + f_r) * 32 + f_k];

#pragma unroll
        for (int m = 0; m < 4; m++)
#pragma unroll
            for (int n = 0; n < 4; n++)
                acc[m][n] = __builtin_amdgcn_mfma_f32_16x16x32_bf16(
                    bfr[n], af[m], acc[m][n], 0, 0, 0);
        __syncthreads();
    }

    const int c_a  = lane & 15;
    const int c_b4 = (lane >> 4) << 2;
#pragma unroll
    for (int m = 0; m < 4; m++) {
        const int gri = (int)(bm * 128) + wr * 64 + m * 16 + c_a;
        if (gri < cnt) {
            const long orow = rowlist[gri];
            float* rp = Cf + orow * LDC;
#pragma unroll
            for (int n = 0; n < 4; n++) {
                const int gcb = (int)(bn * 128) + wc * 64 + n * 16 + c_b4;
                f32x4 v = acc[m][n];
                if (gcb + 3 < width) {
                    __builtin_memcpy(rp + gcb, &v, 16);
                } else {
#pragma unroll
                    for (int j = 0; j < 4; j++)
                        if (gcb + j < width) rp[gcb + j] = v[j];
                }
            }
        }
    }
}

extern "C" void kernel_launch(void* const* d_in, const int* in_sizes, int n_in,
                              void* d_out, int out_size, void* d_ws, size_t ws_size,
                              hipStream_t stream) {
    const float* x      = (const float*)d_in[0];   // [4096,1024]
    const int*   target = (const int*)  d_in[1];   // [4096]
    const float* head_w = (const float*)d_in[2];   // [10002,1024]
    const float* t0_w1  = (const float*)d_in[3];   // [256,1024]
    const float* t0_w2  = (const float*)d_in[4];   // [30000,256]
    const float* t1_w1  = (const float*)d_in[5];   // [64,1024]
    const float* t1_w2  = (const float*)d_in[6];   // [10257,64]
    float* out = (float*)d_out;

    // ---- ws layout (bytes) ----
    char* ws = (char*)d_ws;
    unsigned short* xb    = (unsigned short*)(ws + 0);          // 4096x1024
    unsigned short* hwb   = (unsigned short*)(ws + 8388608);    // 10240x1024
    unsigned short* w01b  = (unsigned short*)(ws + 29360128);   // 512x1024 (t0w1|t1w1|0)
    unsigned short* t0w2b = (unsigned short*)(ws + 30408704);   // 30208x256
    unsigned short* t1w2b = (unsigned short*)(ws + 45875200);   // 10496x64
    unsigned short* h01   = (unsigned short*)(ws + 47218688);   // 4096x384 bf16
    int*            in0   = (int*)(ws + 50364416);              // 4096
    int*            z0l   = (int*)(ws + 50380800);              // 4096
    int*            in1   = (int*)(ws + 50397184);              // 4096
    int*            z1l   = (int*)(ws + 50413568);              // 4096
    int*            cnts  = (int*)(ws + 50429952);              // 2

    // ---- L0: scan (target remap + compaction lists) ----
    scan_kernel<<<1, 1024, 0, stream>>>(target, out + 4096L * LDC,
                                        in0, z0l, in1, z1l, cnts);

    // ---- L1: casts + zero-fill of masked tail rows ----
    CastArgs ca;
    ca.s[0] = {x,      nullptr, xb,    4096,  4096,  524288,  10, 0};
    ca.s[1] = {head_w, nullptr, hwb,   10002, 10002, 1310720, 10, 0};
    ca.s[2] = {t0_w1,  t1_w1,   w01b,  256,   320,   65536,   10, 0};
    ca.s[3] = {t0_w2,  nullptr, t0w2b, 30000, 30000, 966656,  8,  0};
    ca.s[4] = {t1_w2,  nullptr, t1w2b, 10257, 10257, 83968,   6,  0};
    ca.grand8 = 524288 + 1310720 + 65536 + 966656 + 83968;  // 2951168
    ca.z0 = z0l; ca.z1 = z1l; ca.cnts = cnts; ca.out = out;
    cast_fill_kernel<<<10240, 256, 0, stream>>>(ca);

    // ---- L2: head (640 blocks, 8-phase) + h01 (32 blocks) ----
    gemm8_dual_kernel<<<dim3(672), 512, 0, stream>>>(
        xb, hwb, out, 16, 1024, 1024, 10002, 40, 640,
        xb, w01b, h01, 16, 1024, 1024, 384L, 384, 2);

    // ---- L3: compacted tails (worst-case grid, early-exit by cnt) ----
    gemm_tails_kernel<<<dim3(10112), 256, 0, stream>>>(
        h01,       t0w2b, out + 10002, 256, 384, 30000, 235, 7520,
        h01 + 256, t1w2b, out + 40002, 64,  384, 10257, 81,
        in0, in1, cnts);
}